// Round 8
// baseline (264.200 us; speedup 1.0000x reference)
//
#include <hip/hip_runtime.h>
#include <math.h>

#define NN 50000
#define NE 1000000
#define NH 64
#define NKEY 100000      // 2*NN combined key space (src | NN+dst)
#define SPAN 512         // keys per bucket
#define NBKT 196         // ceil(NKEY / SPAN)
#define CAP 12288        // bucket capacity (mean 10240, +20 sigma)
#define CH 34            // LDS staging entries per bucket
#define GNPB 128         // nodes per block in node_gemm
#define GLD 68           // padded leading dim for sh

// ---------- binning helpers -------------------------------------------------
__device__ __forceinline__ void push_pair(int key, int val, int* cnt,
                                          unsigned* buf, int* gcnt,
                                          unsigned* __restrict__ pairs) {
    int b = key >> 9;
    unsigned pk = ((unsigned)val << 9) | (unsigned)(key & 511);
    int slot = atomicAdd(&cnt[b], 1);           // LDS atomic
    if (slot < CH) {
        buf[b * CH + slot] = pk;
    } else {                                     // rare overflow: direct path
        int g = atomicAdd(&gcnt[b], 1);
        if (g < CAP) pairs[(size_t)b * CAP + g] = pk;
    }
}

__device__ __forceinline__ void flush_bins(int* cnt, unsigned* buf, int* gcnt,
                                           unsigned* __restrict__ pairs) {
    __syncthreads();
    int b = threadIdx.x;
    if (b < NBKT) {
        int fc = cnt[b]; if (fc > CH) fc = CH;
        if (fc > 0) {
            int g = atomicAdd(&gcnt[b], fc);     // one global atomic per run
            for (int t = 0; t < fc; ++t)
                if (g + t < CAP)
                    pairs[(size_t)b * CAP + g + t] = buf[b * CH + t];
            cnt[b] = 0;
        }
    }
    __syncthreads();
}

// ---------- pass 1: LDS-staged binning of 2M (key,val) pairs ----------------
__global__ __launch_bounds__(256) void bin_pass(
    const int* __restrict__ src, const int* __restrict__ dst,
    int* __restrict__ gcnt, unsigned* __restrict__ pairs) {
    __shared__ int cnt[NBKT];
    __shared__ unsigned buf[NBKT * CH];
    for (int b = threadIdx.x; b < NBKT; b += 256) cnt[b] = 0;
    __syncthreads();
    int r = 0;
    for (int base = blockIdx.x * 256; base < NE; base += gridDim.x * 256) {
        int e = base + threadIdx.x;
        if (e < NE) {
            int s = src[e], d = dst[e];
            push_pair(s, d, cnt, buf, gcnt, pairs);       // out-edge of s
            push_pair(NN + d, s, cnt, buf, gcnt, pairs);  // in-edge of d
        }
        if ((++r & 7) == 0) flush_bins(cnt, buf, gcnt, pairs);
    }
    flush_bins(cnt, buf, gcnt, pairs);
}

// ---------- pass 2: scan 196 bucket counts ----------------------------------
__global__ __launch_bounds__(256) void bucket_scan(
    const int* __restrict__ gcnt, int* __restrict__ gbase,
    int* __restrict__ off) {
    __shared__ int tmp[256];
    int t = threadIdx.x;
    int v = (t < NBKT) ? gcnt[t] : 0;
    tmp[t] = v;
    __syncthreads();
    for (int o = 1; o < 256; o <<= 1) {
        int u = (t >= o) ? tmp[t - o] : 0;
        __syncthreads();
        tmp[t] += u;
        __syncthreads();
    }
    if (t < NBKT) gbase[t] = tmp[t] - v;   // exclusive prefix
    if (t == 0) off[NKEY] = 2 * NE;        // sentinel
}

// ---------- pass 3: per-bucket counting sort + off/csr emission -------------
__global__ __launch_bounds__(1024) void sort_pass(
    const unsigned* __restrict__ pairs, const int* __restrict__ gcnt,
    const int* __restrict__ gbase, int* __restrict__ off,
    int* __restrict__ csr) {
    __shared__ int hist[SPAN];
    __shared__ int scn[SPAN];
    int k = blockIdx.x;
    int t = threadIdx.x;
    int n = gcnt[k]; if (n > CAP) n = CAP;
    int base = gbase[k];
    const unsigned* bp = pairs + (size_t)k * CAP;

    if (t < SPAN) hist[t] = 0;
    __syncthreads();
    for (int i = t; i < n; i += 1024)
        atomicAdd(&hist[bp[i] & 511], 1);
    __syncthreads();
    if (t < SPAN) scn[t] = hist[t];
    __syncthreads();
    for (int o = 1; o < SPAN; o <<= 1) {
        int u = 0;
        if (t < SPAN && t >= o) u = scn[t - o];
        __syncthreads();
        if (t < SPAN) scn[t] += u;
        __syncthreads();
    }
    if (t < SPAN) {
        int ex = base + scn[t] - hist[t];   // absolute exclusive prefix
        int gk = k * SPAN + t;
        if (gk < NKEY) off[gk] = ex;
        scn[t] = ex;                        // reuse as cursor
    }
    __syncthreads();
    for (int i = t; i < n; i += 1024) {
        unsigned p = bp[i];
        int pos = atomicAdd(&scn[p & 511], 1);   // LDS atomic
        csr[pos] = (int)(p >> 9);                // block-local global store
    }
}

// clamp gathered index (protects rocprof dispatch-replay from stale buffers;
// compiles to v_med3_i32, free in a latency-bound gather loop)
__device__ __forceinline__ int cidx(int i) {
    return max(0, min(i, NN - 1));
}

// ---------- pass 4: wave-per-node gather-mean, 8-deep ILP -------------------
__global__ __launch_bounds__(256) void gather_mean(
    const float* __restrict__ X, const int* __restrict__ off_dst,
    const int* __restrict__ csr, float* __restrict__ M) {
    int wid = (int)(((long long)blockIdx.x * blockDim.x + threadIdx.x) >> 6);
    int j = threadIdx.x & 63;
    if (wid >= NN) return;
    int e0 = off_dst[wid], e1 = off_dst[wid + 1];
    const float* Xj = X + j;
    float s0 = 0, s1 = 0, s2 = 0, s3 = 0, s4 = 0, s5 = 0, s6 = 0, s7 = 0;
    int e = e0;
    for (; e + 8 <= e1; e += 8) {
        int i0 = cidx(csr[e + 0]), i1 = cidx(csr[e + 1]);
        int i2 = cidx(csr[e + 2]), i3 = cidx(csr[e + 3]);
        int i4 = cidx(csr[e + 4]), i5 = cidx(csr[e + 5]);
        int i6 = cidx(csr[e + 6]), i7 = cidx(csr[e + 7]);
        s0 += Xj[(size_t)i0 * NH]; s1 += Xj[(size_t)i1 * NH];
        s2 += Xj[(size_t)i2 * NH]; s3 += Xj[(size_t)i3 * NH];
        s4 += Xj[(size_t)i4 * NH]; s5 += Xj[(size_t)i5 * NH];
        s6 += Xj[(size_t)i6 * NH]; s7 += Xj[(size_t)i7 * NH];
    }
    for (; e < e1; ++e) s0 += Xj[(size_t)cidx(csr[e]) * NH];
    float sum = ((s0 + s1) + (s2 + s3)) + ((s4 + s5) + (s6 + s7));
    M[(size_t)wid * NH + j] = sum / fmaxf((float)(e1 - e0), 1.0f);
}

// ---------- pass 5: node GEMM v4 --------------------------------------------
// 256 threads, 128 nodes/block, 8x4 register tile per thread.
// x/mean read straight from global (16-lane broadcast, L1/L2-served);
// LDS holds only weights (32 KB, two-stage) + h (34 KB) -> 2 blocks/CU.
__device__ __forceinline__ int shrow(int node) {   // bank-spread row remap
    return (node & 7) * 16 + (node >> 3);
}

__global__ __launch_bounds__(256, 2) void node_gemm(
    const float* __restrict__ X, float* MA /* in: mean, out: A (aliased) */,
    const float* __restrict__ Wself, const float* __restrict__ Wneigh,
    const float* __restrict__ bsage, const float* __restrict__ Qw,
    float* __restrict__ B) {
    __shared__ __align__(16) float sWa[4096];       // Ws, then Q1  [k][j]
    __shared__ __align__(16) float sWb[4096];       // Wn, then Q2  [k][j]
    __shared__ __align__(16) float sh[GNPB * GLD];  // h [shrow(node)][j]

    const int T  = threadIdx.x;
    const int tj = T & 15;          // cols 4*tj..4*tj+3
    const int tn = T >> 4;          // nodes 8*tn..8*tn+7 (tn 0..15)
    const int nbase = blockIdx.x * GNPB;

    #pragma unroll
    for (int r = 0; r < 4; ++r) {
        int i = r * 256 + T;
        ((float4*)sWa)[i] = ((const float4*)Wself)[i];
        ((float4*)sWb)[i] = ((const float4*)Wneigh)[i];
    }
    __syncthreads();

    int gn[8];
    #pragma unroll
    for (int ni = 0; ni < 8; ++ni) {
        int n = nbase + tn * 8 + ni;
        gn[ni] = n < NN ? n : NN - 1;
    }

    float4 bv = ((const float4*)bsage)[tj];
    float acc[8][4];
    #pragma unroll
    for (int ni = 0; ni < 8; ++ni) {
        acc[ni][0] = bv.x; acc[ni][1] = bv.y;
        acc[ni][2] = bv.z; acc[ni][3] = bv.w;
    }

#define LOADC(xb, mb, kq)                                            \
    _Pragma("unroll")                                                \
    for (int ni = 0; ni < 8; ++ni) {                                 \
        xb[ni] = *(const float4*)&X[(size_t)gn[ni] * NH + (kq)];     \
        mb[ni] = *(const float4*)&MA[(size_t)gn[ni] * NH + (kq)];    \
    }

#define FMAC(xb, mb, kq)                                             \
    {                                                                \
        float4 wa[4], wb4[4];                                        \
        _Pragma("unroll")                                            \
        for (int kk = 0; kk < 4; ++kk) {                             \
            wa[kk]  = ((const float4*)sWa)[((kq) + kk) * 16 + tj];   \
            wb4[kk] = ((const float4*)sWb)[((kq) + kk) * 16 + tj];   \
        }                                                            \
        _Pragma("unroll")                                            \
        for (int ni = 0; ni < 8; ++ni)                               \
            _Pragma("unroll")                                        \
            for (int kk = 0; kk < 4; ++kk) {                         \
                float xs = ((const float*)&xb[ni])[kk];              \
                float ms = ((const float*)&mb[ni])[kk];              \
                _Pragma("unroll")                                    \
                for (int ji = 0; ji < 4; ++ji)                       \
                    acc[ni][ji] += xs * ((const float*)&wa[kk])[ji]  \
                                 + ms * ((const float*)&wb4[kk])[ji];\
            }                                                        \
    }

    // ---- phase 1: h = relu(x Ws + m Wn + b), 2-deep load pipeline ----
    {
        float4 xa[8], ma[8], xb[8], mb[8];
        LOADC(xa, ma, 0)
        for (int k0 = 0; k0 < 64; k0 += 8) {
            LOADC(xb, mb, k0 + 4)
            FMAC(xa, ma, k0)
            if (k0 + 8 < 64) { LOADC(xa, ma, k0 + 8) }
            FMAC(xb, mb, k0 + 4)
        }
    }

    // write h into sh (bank-spread rows)
    #pragma unroll
    for (int ni = 0; ni < 8; ++ni) {
        float4 hv;
        hv.x = fmaxf(acc[ni][0], 0.0f);
        hv.y = fmaxf(acc[ni][1], 0.0f);
        hv.z = fmaxf(acc[ni][2], 0.0f);
        hv.w = fmaxf(acc[ni][3], 0.0f);
        *(float4*)&sh[shrow(tn * 8 + ni) * GLD + tj * 4] = hv;
    }
    __syncthreads();   // weight reads + sh writes complete

    // re-stage Q1/Q2 over Ws/Wn
    #pragma unroll
    for (int r = 0; r < 4; ++r) {
        int i = r * 256 + T;
        ((float4*)sWa)[i] = ((const float4*)Qw)[i];           // rows 0..63
        ((float4*)sWb)[i] = ((const float4*)(Qw + 4096))[i];  // rows 64..127
    }
    __syncthreads();

    // ---- phase 2: A = h Q1, B = h Q2 ----
    float aA[8][4], aB[8][4];
    #pragma unroll
    for (int ni = 0; ni < 8; ++ni)
        #pragma unroll
        for (int ji = 0; ji < 4; ++ji) { aA[ni][ji] = 0.0f; aB[ni][ji] = 0.0f; }

    for (int j0 = 0; j0 < 64; j0 += 4) {
        float4 hr[8], q1[4], q2[4];
        #pragma unroll
        for (int ni = 0; ni < 8; ++ni)
            hr[ni] = *(const float4*)&sh[shrow(tn * 8 + ni) * GLD + j0];
        #pragma unroll
        for (int jj = 0; jj < 4; ++jj) {
            q1[jj] = ((const float4*)sWa)[(j0 + jj) * 16 + tj];
            q2[jj] = ((const float4*)sWb)[(j0 + jj) * 16 + tj];
        }
        #pragma unroll
        for (int ni = 0; ni < 8; ++ni)
            #pragma unroll
            for (int jj = 0; jj < 4; ++jj) {
                float hs = ((const float*)&hr[ni])[jj];
                #pragma unroll
                for (int ji = 0; ji < 4; ++ji) {
                    aA[ni][ji] += hs * ((const float*)&q1[jj])[ji];
                    aB[ni][ji] += hs * ((const float*)&q2[jj])[ji];
                }
            }
    }

    // store A (over mean) and B
    #pragma unroll
    for (int ni = 0; ni < 8; ++ni) {
        int n = nbase + tn * 8 + ni;
        if (n < NN) {
            float4 va, vb;
            va.x = aA[ni][0]; va.y = aA[ni][1]; va.z = aA[ni][2]; va.w = aA[ni][3];
            vb.x = aB[ni][0]; vb.y = aB[ni][1]; vb.z = aB[ni][2]; vb.w = aB[ni][3];
            *(float4*)&MA[(size_t)n * NH + tj * 4] = va;
            *(float4*)&B[(size_t)n * NH + tj * 4] = vb;
        }
    }
#undef LOADC
#undef FMAC
}

// ---------- pass 6: wave-per-node out-edge reduction, 8-deep ILP ------------
__global__ __launch_bounds__(256) void edge_out(
    const float* __restrict__ A, const float* __restrict__ B,
    const float* __restrict__ Qb, const int* __restrict__ off_src,
    const int* __restrict__ csr, float* __restrict__ out) {
    int wid = (int)(((long long)blockIdx.x * blockDim.x + threadIdx.x) >> 6);
    int j = threadIdx.x & 63;
    if (wid >= NN) return;
    float aq = A[(size_t)wid * NH + j] + Qb[j];
    int e0 = off_src[wid], e1 = off_src[wid + 1];
    const float* Bj = B + j;
    float s0 = 0, s1 = 0, s2 = 0, s3 = 0, s4 = 0, s5 = 0, s6 = 0, s7 = 0;
    int e = e0;
    for (; e + 8 <= e1; e += 8) {
        int i0 = cidx(csr[e + 0]), i1 = cidx(csr[e + 1]);
        int i2 = cidx(csr[e + 2]), i3 = cidx(csr[e + 3]);
        int i4 = cidx(csr[e + 4]), i5 = cidx(csr[e + 5]);
        int i6 = cidx(csr[e + 6]), i7 = cidx(csr[e + 7]);
        float t0 = aq + Bj[(size_t)i0 * NH]; s0 += t0 * t0;
        float t1 = aq + Bj[(size_t)i1 * NH]; s1 += t1 * t1;
        float t2 = aq + Bj[(size_t)i2 * NH]; s2 += t2 * t2;
        float t3 = aq + Bj[(size_t)i3 * NH]; s3 += t3 * t3;
        float t4 = aq + Bj[(size_t)i4 * NH]; s4 += t4 * t4;
        float t5 = aq + Bj[(size_t)i5 * NH]; s5 += t5 * t5;
        float t6 = aq + Bj[(size_t)i6 * NH]; s6 += t6 * t6;
        float t7 = aq + Bj[(size_t)i7 * NH]; s7 += t7 * t7;
    }
    for (; e < e1; ++e) {
        float t = aq + Bj[(size_t)cidx(csr[e]) * NH];
        s0 += t * t;
    }
    float acc = ((s0 + s1) + (s2 + s3)) + ((s4 + s5) + (s6 + s7));
    out[(size_t)wid * NH + j] = tanhf(acc / fmaxf((float)(e1 - e0), 1.0f));
}

extern "C" void kernel_launch(void* const* d_in, const int* in_sizes, int n_in,
                              void* d_out, int out_size, void* d_ws, size_t ws_size,
                              hipStream_t stream) {
    const float* X      = (const float*)d_in[0];
    const int*   ei     = (const int*)d_in[1];   // [2, NE] int32
    const float* Wself  = (const float*)d_in[2];
    const float* Wneigh = (const float*)d_in[3];
    const float* bsage  = (const float*)d_in[4];
    const float* Qw     = (const float*)d_in[5];
    const float* Qb     = (const float*)d_in[6];
    const int* src = ei;
    const int* dst = ei + NE;

    float* out = (float*)d_out;

    // workspace layout (~44 MB)
    float* A = (float*)d_ws;                         // NN*NH floats
    float* B = A + (size_t)NN * NH;                  // NN*NH floats
    unsigned* pairs = (unsigned*)(B + (size_t)NN * NH); // NBKT*CAP u32
    int* csr   = (int*)(pairs + (size_t)NBKT * CAP); // 2*NE
    int* off   = csr + 2 * NE;                       // NKEY+1
    int* gcnt  = off + NKEY + 1;                     // NBKT
    int* gbase = gcnt + NBKT;                        // NBKT

    hipMemsetAsync(gcnt, 0, NBKT * sizeof(int), stream);

    bin_pass<<<512, 256, 0, stream>>>(src, dst, gcnt, pairs);
    bucket_scan<<<1, 256, 0, stream>>>(gcnt, gbase, off);
    sort_pass<<<NBKT, 1024, 0, stream>>>(pairs, gcnt, gbase, off, csr);
    gather_mean<<<(NN + 3) / 4, 256, 0, stream>>>(X, off + NN, csr, A);
    node_gemm<<<(NN + GNPB - 1) / GNPB, 256, 0, stream>>>(X, A, Wself, Wneigh,
                                                          bsage, Qw, B);
    edge_out<<<(NN + 3) / 4, 256, 0, stream>>>(A, B, Qb, off, csr, out);
}

// Round 9
// 173.712 us; speedup vs baseline: 1.5209x; 1.5209x over previous
//
#include <hip/hip_runtime.h>
#include <math.h>

#define NN 50000
#define NE 1000000
#define NH 64
#define NKEY 100000      // 2*NN combined key space (src | NN+dst)
#define SPAN 512         // keys per bucket
#define NBKT 196         // ceil(NKEY / SPAN)
#define CAP 12288        // bucket capacity (mean 10240, +20 sigma)
#define CH 34            // LDS staging entries per bucket
#define GNPB 64          // nodes per block in node_gemm
#define GLD 68           // padded leading dim for LDS tiles

// ---------- binning helpers -------------------------------------------------
__device__ __forceinline__ void push_pair(int key, int val, int* cnt,
                                          unsigned* buf, int* gcnt,
                                          unsigned* __restrict__ pairs) {
    int b = key >> 9;
    unsigned pk = ((unsigned)val << 9) | (unsigned)(key & 511);
    int slot = atomicAdd(&cnt[b], 1);           // LDS atomic
    if (slot < CH) {
        buf[b * CH + slot] = pk;
    } else {                                     // rare overflow: direct path
        int g = atomicAdd(&gcnt[b], 1);
        if (g < CAP) pairs[(size_t)b * CAP + g] = pk;
    }
}

__device__ __forceinline__ void flush_bins(int* cnt, unsigned* buf, int* gcnt,
                                           unsigned* __restrict__ pairs) {
    __syncthreads();
    int b = threadIdx.x;
    if (b < NBKT) {
        int fc = cnt[b]; if (fc > CH) fc = CH;
        if (fc > 0) {
            int g = atomicAdd(&gcnt[b], fc);     // one global atomic per run
            for (int t = 0; t < fc; ++t)
                if (g + t < CAP)
                    pairs[(size_t)b * CAP + g + t] = buf[b * CH + t];
            cnt[b] = 0;
        }
    }
    __syncthreads();
}

// ---------- pass 1: LDS-staged binning of 2M (key,val) pairs ----------------
__global__ __launch_bounds__(256) void bin_pass(
    const int* __restrict__ src, const int* __restrict__ dst,
    int* __restrict__ gcnt, unsigned* __restrict__ pairs) {
    __shared__ int cnt[NBKT];
    __shared__ unsigned buf[NBKT * CH];
    for (int b = threadIdx.x; b < NBKT; b += 256) cnt[b] = 0;
    __syncthreads();
    int r = 0;
    for (int base = blockIdx.x * 256; base < NE; base += gridDim.x * 256) {
        int e = base + threadIdx.x;
        if (e < NE) {
            int s = src[e], d = dst[e];
            push_pair(s, d, cnt, buf, gcnt, pairs);       // out-edge of s
            push_pair(NN + d, s, cnt, buf, gcnt, pairs);  // in-edge of d
        }
        if ((++r & 7) == 0) flush_bins(cnt, buf, gcnt, pairs);
    }
    flush_bins(cnt, buf, gcnt, pairs);
}

// ---------- pass 2: scan 196 bucket counts ----------------------------------
__global__ __launch_bounds__(256) void bucket_scan(
    const int* __restrict__ gcnt, int* __restrict__ gbase,
    int* __restrict__ off) {
    __shared__ int tmp[256];
    int t = threadIdx.x;
    int v = (t < NBKT) ? gcnt[t] : 0;
    tmp[t] = v;
    __syncthreads();
    for (int o = 1; o < 256; o <<= 1) {
        int u = (t >= o) ? tmp[t - o] : 0;
        __syncthreads();
        tmp[t] += u;
        __syncthreads();
    }
    if (t < NBKT) gbase[t] = tmp[t] - v;   // exclusive prefix
    if (t == 0) off[NKEY] = 2 * NE;        // sentinel
}

// ---------- pass 3: per-bucket counting sort + off/csr emission -------------
__global__ __launch_bounds__(1024) void sort_pass(
    const unsigned* __restrict__ pairs, const int* __restrict__ gcnt,
    const int* __restrict__ gbase, int* __restrict__ off,
    int* __restrict__ csr) {
    __shared__ int hist[SPAN];
    __shared__ int scn[SPAN];
    int k = blockIdx.x;
    int t = threadIdx.x;
    int n = gcnt[k]; if (n > CAP) n = CAP;
    int base = gbase[k];
    const unsigned* bp = pairs + (size_t)k * CAP;

    if (t < SPAN) hist[t] = 0;
    __syncthreads();
    for (int i = t; i < n; i += 1024)
        atomicAdd(&hist[bp[i] & 511], 1);
    __syncthreads();
    if (t < SPAN) scn[t] = hist[t];
    __syncthreads();
    for (int o = 1; o < SPAN; o <<= 1) {
        int u = 0;
        if (t < SPAN && t >= o) u = scn[t - o];
        __syncthreads();
        if (t < SPAN) scn[t] += u;
        __syncthreads();
    }
    if (t < SPAN) {
        int ex = base + scn[t] - hist[t];   // absolute exclusive prefix
        int gk = k * SPAN + t;
        if (gk < NKEY) off[gk] = ex;
        scn[t] = ex;                        // reuse as cursor
    }
    __syncthreads();
    for (int i = t; i < n; i += 1024) {
        unsigned p = bp[i];
        int pos = atomicAdd(&scn[p & 511], 1);   // LDS atomic
        csr[pos] = (int)(p >> 9);                // block-local global store
    }
}

// clamp gathered index (protects rocprof dispatch-replay from stale buffers;
// compiles to v_med3_i32, free in a latency-bound gather loop)
__device__ __forceinline__ int cidx(int i) {
    return max(0, min(i, NN - 1));
}

// ---------- pass 4: wave-per-node gather-mean, 8-deep ILP -------------------
__global__ __launch_bounds__(256) void gather_mean(
    const float* __restrict__ X, const int* __restrict__ off_dst,
    const int* __restrict__ csr, float* __restrict__ M) {
    int wid = (int)(((long long)blockIdx.x * blockDim.x + threadIdx.x) >> 6);
    int j = threadIdx.x & 63;
    if (wid >= NN) return;
    int e0 = off_dst[wid], e1 = off_dst[wid + 1];
    const float* Xj = X + j;
    float s0 = 0, s1 = 0, s2 = 0, s3 = 0, s4 = 0, s5 = 0, s6 = 0, s7 = 0;
    int e = e0;
    for (; e + 8 <= e1; e += 8) {
        int i0 = cidx(csr[e + 0]), i1 = cidx(csr[e + 1]);
        int i2 = cidx(csr[e + 2]), i3 = cidx(csr[e + 3]);
        int i4 = cidx(csr[e + 4]), i5 = cidx(csr[e + 5]);
        int i6 = cidx(csr[e + 6]), i7 = cidx(csr[e + 7]);
        s0 += Xj[(size_t)i0 * NH]; s1 += Xj[(size_t)i1 * NH];
        s2 += Xj[(size_t)i2 * NH]; s3 += Xj[(size_t)i3 * NH];
        s4 += Xj[(size_t)i4 * NH]; s5 += Xj[(size_t)i5 * NH];
        s6 += Xj[(size_t)i6 * NH]; s7 += Xj[(size_t)i7 * NH];
    }
    for (; e < e1; ++e) s0 += Xj[(size_t)cidx(csr[e]) * NH];
    float sum = ((s0 + s1) + (s2 + s3)) + ((s4 + s5) + (s6 + s7));
    M[(size_t)wid * NH + j] = sum / fmaxf((float)(e1 - e0), 1.0f);
}

// ---------- pass 5: node GEMM v5 — LDS-tiled, 64 nodes/block, 2 blocks/CU ---
// 256 threads, 4x4 register tile. Two-stage weights: Ws/Wn for phase 1,
// Q1/Q2 re-staged into the same 32 KB for phase 2. LDS total 67 KB.
__global__ __launch_bounds__(256, 2) void node_gemm(
    const float* __restrict__ X, float* MA /* in: mean, out: A (aliased) */,
    const float* __restrict__ Wself, const float* __restrict__ Wneigh,
    const float* __restrict__ bsage, const float* __restrict__ Qw,
    float* __restrict__ B) {
    __shared__ __align__(16) float sWa[4096];       // Ws, then Q1  [k][j]
    __shared__ __align__(16) float sWb[4096];       // Wn, then Q2  [k][j]
    __shared__ __align__(16) float sx[GNPB * GLD];  // x [node][k]
    __shared__ __align__(16) float sh[GNPB * GLD];  // mean, then h [node][j]

    const int T  = threadIdx.x;
    const int tj = T & 15;          // cols 4*tj..4*tj+3
    const int tn = T >> 4;          // nodes 4*tn..4*tn+3 (tn 0..15)
    const int nbase = blockIdx.x * GNPB;

    // stage Ws, Wn (1024 float4 each)
    #pragma unroll
    for (int r = 0; r < 4; ++r) {
        int i = r * 256 + T;
        ((float4*)sWa)[i] = ((const float4*)Wself)[i];
        ((float4*)sWb)[i] = ((const float4*)Wneigh)[i];
    }
    // stage x, mean row-major (coalesced float4; 64 nodes x 16 float4)
    #pragma unroll
    for (int r = 0; r < 4; ++r) {
        int F = r * 256 + T;        // 0..1023
        int node = F >> 4;          // 0..63
        int k4 = F & 15;
        int gn = nbase + node; if (gn > NN - 1) gn = NN - 1;
        float4 xv = ((const float4*)&X[(size_t)gn * NH])[k4];
        float4 mv = ((const float4*)&MA[(size_t)gn * NH])[k4];
        *(float4*)&sx[node * GLD + k4 * 4] = xv;
        *(float4*)&sh[node * GLD + k4 * 4] = mv;
    }
    __syncthreads();

    // ---- phase 1: h = relu(x Ws + m Wn + b) ----
    float4 bv = ((const float4*)bsage)[tj];
    const float* bp = (const float*)&bv;
    float acc[4][4];
    #pragma unroll
    for (int ni = 0; ni < 4; ++ni)
        #pragma unroll
        for (int ji = 0; ji < 4; ++ji) acc[ni][ji] = bp[ji];

    for (int k0 = 0; k0 < 64; k0 += 4) {
        float4 xr[4], mr[4], wa[4], wb[4];
        #pragma unroll
        for (int ni = 0; ni < 4; ++ni) {
            xr[ni] = *(const float4*)&sx[(tn * 4 + ni) * GLD + k0];
            mr[ni] = *(const float4*)&sh[(tn * 4 + ni) * GLD + k0];
        }
        #pragma unroll
        for (int kk = 0; kk < 4; ++kk) {
            wa[kk] = ((const float4*)sWa)[(k0 + kk) * 16 + tj];
            wb[kk] = ((const float4*)sWb)[(k0 + kk) * 16 + tj];
        }
        #pragma unroll
        for (int ni = 0; ni < 4; ++ni)
            #pragma unroll
            for (int kk = 0; kk < 4; ++kk) {
                float xs = ((const float*)&xr[ni])[kk];
                float ms = ((const float*)&mr[ni])[kk];
                #pragma unroll
                for (int ji = 0; ji < 4; ++ji)
                    acc[ni][ji] += xs * ((const float*)&wa[kk])[ji]
                                 + ms * ((const float*)&wb[kk])[ji];
            }
    }
    __syncthreads();   // all sh(mean) + weight reads done

    // write h = relu(acc) into sh; re-stage Q1/Q2 over Ws/Wn
    #pragma unroll
    for (int ni = 0; ni < 4; ++ni) {
        float4 hv;
        hv.x = fmaxf(acc[ni][0], 0.0f);
        hv.y = fmaxf(acc[ni][1], 0.0f);
        hv.z = fmaxf(acc[ni][2], 0.0f);
        hv.w = fmaxf(acc[ni][3], 0.0f);
        *(float4*)&sh[(tn * 4 + ni) * GLD + tj * 4] = hv;
    }
    #pragma unroll
    for (int r = 0; r < 4; ++r) {
        int i = r * 256 + T;
        ((float4*)sWa)[i] = ((const float4*)Qw)[i];           // rows 0..63
        ((float4*)sWb)[i] = ((const float4*)(Qw + 4096))[i];  // rows 64..127
    }
    __syncthreads();

    // ---- phase 2: A = h Q1, B = h Q2 ----
    float aA[4][4], aB[4][4];
    #pragma unroll
    for (int ni = 0; ni < 4; ++ni)
        #pragma unroll
        for (int ji = 0; ji < 4; ++ji) { aA[ni][ji] = 0.0f; aB[ni][ji] = 0.0f; }

    for (int j0 = 0; j0 < 64; j0 += 4) {
        float4 hr[4], q1[4], q2[4];
        #pragma unroll
        for (int ni = 0; ni < 4; ++ni)
            hr[ni] = *(const float4*)&sh[(tn * 4 + ni) * GLD + j0];
        #pragma unroll
        for (int jj = 0; jj < 4; ++jj) {
            q1[jj] = ((const float4*)sWa)[(j0 + jj) * 16 + tj];
            q2[jj] = ((const float4*)sWb)[(j0 + jj) * 16 + tj];
        }
        #pragma unroll
        for (int ni = 0; ni < 4; ++ni)
            #pragma unroll
            for (int jj = 0; jj < 4; ++jj) {
                float hs = ((const float*)&hr[ni])[jj];
                #pragma unroll
                for (int ji = 0; ji < 4; ++ji) {
                    aA[ni][ji] += hs * ((const float*)&q1[jj])[ji];
                    aB[ni][ji] += hs * ((const float*)&q2[jj])[ji];
                }
            }
    }

    // store A (over mean) and B
    #pragma unroll
    for (int ni = 0; ni < 4; ++ni) {
        int gn = nbase + tn * 4 + ni;
        if (gn < NN) {
            float4 va, vb;
            va.x = aA[ni][0]; va.y = aA[ni][1]; va.z = aA[ni][2]; va.w = aA[ni][3];
            vb.x = aB[ni][0]; vb.y = aB[ni][1]; vb.z = aB[ni][2]; vb.w = aB[ni][3];
            *(float4*)&MA[(size_t)gn * NH + tj * 4] = va;
            *(float4*)&B[(size_t)gn * NH + tj * 4] = vb;
        }
    }
}

// ---------- pass 6: wave-per-node out-edge reduction, 8-deep ILP ------------
__global__ __launch_bounds__(256) void edge_out(
    const float* __restrict__ A, const float* __restrict__ B,
    const float* __restrict__ Qb, const int* __restrict__ off_src,
    const int* __restrict__ csr, float* __restrict__ out) {
    int wid = (int)(((long long)blockIdx.x * blockDim.x + threadIdx.x) >> 6);
    int j = threadIdx.x & 63;
    if (wid >= NN) return;
    float aq = A[(size_t)wid * NH + j] + Qb[j];
    int e0 = off_src[wid], e1 = off_src[wid + 1];
    const float* Bj = B + j;
    float s0 = 0, s1 = 0, s2 = 0, s3 = 0, s4 = 0, s5 = 0, s6 = 0, s7 = 0;
    int e = e0;
    for (; e + 8 <= e1; e += 8) {
        int i0 = cidx(csr[e + 0]), i1 = cidx(csr[e + 1]);
        int i2 = cidx(csr[e + 2]), i3 = cidx(csr[e + 3]);
        int i4 = cidx(csr[e + 4]), i5 = cidx(csr[e + 5]);
        int i6 = cidx(csr[e + 6]), i7 = cidx(csr[e + 7]);
        float t0 = aq + Bj[(size_t)i0 * NH]; s0 += t0 * t0;
        float t1 = aq + Bj[(size_t)i1 * NH]; s1 += t1 * t1;
        float t2 = aq + Bj[(size_t)i2 * NH]; s2 += t2 * t2;
        float t3 = aq + Bj[(size_t)i3 * NH]; s3 += t3 * t3;
        float t4 = aq + Bj[(size_t)i4 * NH]; s4 += t4 * t4;
        float t5 = aq + Bj[(size_t)i5 * NH]; s5 += t5 * t5;
        float t6 = aq + Bj[(size_t)i6 * NH]; s6 += t6 * t6;
        float t7 = aq + Bj[(size_t)i7 * NH]; s7 += t7 * t7;
    }
    for (; e < e1; ++e) {
        float t = aq + Bj[(size_t)cidx(csr[e]) * NH];
        s0 += t * t;
    }
    float acc = ((s0 + s1) + (s2 + s3)) + ((s4 + s5) + (s6 + s7));
    out[(size_t)wid * NH + j] = tanhf(acc / fmaxf((float)(e1 - e0), 1.0f));
}

extern "C" void kernel_launch(void* const* d_in, const int* in_sizes, int n_in,
                              void* d_out, int out_size, void* d_ws, size_t ws_size,
                              hipStream_t stream) {
    const float* X      = (const float*)d_in[0];
    const int*   ei     = (const int*)d_in[1];   // [2, NE] int32
    const float* Wself  = (const float*)d_in[2];
    const float* Wneigh = (const float*)d_in[3];
    const float* bsage  = (const float*)d_in[4];
    const float* Qw     = (const float*)d_in[5];
    const float* Qb     = (const float*)d_in[6];
    const int* src = ei;
    const int* dst = ei + NE;

    float* out = (float*)d_out;

    // workspace layout (~44 MB)
    float* A = (float*)d_ws;                         // NN*NH floats
    float* B = A + (size_t)NN * NH;                  // NN*NH floats
    unsigned* pairs = (unsigned*)(B + (size_t)NN * NH); // NBKT*CAP u32
    int* csr   = (int*)(pairs + (size_t)NBKT * CAP); // 2*NE
    int* off   = csr + 2 * NE;                       // NKEY+1
    int* gcnt  = off + NKEY + 1;                     // NBKT
    int* gbase = gcnt + NBKT;                        // NBKT

    hipMemsetAsync(gcnt, 0, NBKT * sizeof(int), stream);

    bin_pass<<<512, 256, 0, stream>>>(src, dst, gcnt, pairs);
    bucket_scan<<<1, 256, 0, stream>>>(gcnt, gbase, off);
    sort_pass<<<NBKT, 1024, 0, stream>>>(pairs, gcnt, gbase, off, csr);
    gather_mean<<<(NN + 3) / 4, 256, 0, stream>>>(X, off + NN, csr, A);
    node_gemm<<<(NN + GNPB - 1) / GNPB, 256, 0, stream>>>(X, A, Wself, Wneigh,
                                                          bsage, Qw, B);
    edge_out<<<(NN + 3) / 4, 256, 0, stream>>>(A, B, Qb, off, csr, out);
}